// Round 3
// baseline (997.734 us; speedup 1.0000x reference)
//
#include <hip/hip_runtime.h>
#include <math.h>

#define B_ 8
#define L_ 2048
#define DM 6
#define ED 48
#define NS 32
#define DCONV 16
#define NLAYERS 4
#define NCLASSES 4
#define EPS 1e-5f

#define CH 32              // chunks per chain
#define CL (L_ / CH)       // 64 steps per chunk
#define NBLK 512           // == NPRE; 2 blocks/CU guaranteed co-resident
#define NSCANTASK ((B_ * ED * CH * NS) / 256)  // 1536 scan tasks of 256 thr

// workspace: 5,177,344 floats of buffers + barrier area
#define WS_FLOATS 5177344
#define BAR_EPOCHS 12
#define BAR_SLOT_U32 16            // 64B padding per counter
#define BAR_SLOTS 9                // 8 leaves + 1 master per epoch
#define BAR_BYTES (BAR_EPOCHS * BAR_SLOTS * BAR_SLOT_U32 * 4)

// Hand-rolled grid barrier (cooperative launch is rejected by the harness;
// rounds 1-2 showed bit-identical "output==0" failures -> launch never ran).
// Per-epoch monotone counters: no reset, no sense reversal. Two-level to
// avoid 512 serialized same-line atomics. __threadfence() = agent-scope
// fence -> L2 writeback/invalidate handles cross-XCD visibility (G16);
// __syncthreads() has already drained each wave's vmcnt, so all the XCD's
// stores are in L2 when the cache-wide writeback executes.
__device__ __forceinline__ void grid_barrier(unsigned* bar, int epoch)
{
    __syncthreads();
    if (threadIdx.x == 0) {
        unsigned* leaf   = bar + (epoch * BAR_SLOTS + (blockIdx.x & 7)) * BAR_SLOT_U32;
        unsigned* master = bar + (epoch * BAR_SLOTS + 8) * BAR_SLOT_U32;
        __threadfence();                       // release: flush this XCD's L2
        if (atomicAdd(leaf, 1u) == (NBLK / 8) - 1)
            atomicAdd(master, 1u);             // last arrival of this leaf
        while (__hip_atomic_load(master, __ATOMIC_ACQUIRE,
                                 __HIP_MEMORY_SCOPE_AGENT) < 8u)
            __builtin_amdgcn_s_sleep(8);
        __threadfence();                       // acquire: invalidate stale L2
    }
    __syncthreads();
}

// Layouts:
//   h, z, xc, delta, y : [b][feat][l]   (l contiguous)
//   Bm, Cm             : [b][l][n]      (n contiguous)
__global__ void __launch_bounds__(256, 2) k_all(
    const float* __restrict__ x,
    const float* __restrict__ in_proj_w,
    const float* __restrict__ conv_w,
    const float* __restrict__ conv_b,
    const float* __restrict__ x_proj_w,
    const float* __restrict__ dt_proj_w,
    const float* __restrict__ dt_proj_b,
    const float* __restrict__ A_log,
    const float* __restrict__ Dp,
    const float* __restrict__ out_proj_w,
    const float* __restrict__ norm_w,
    const float* __restrict__ fc_w,
    const float* __restrict__ fc_b,
    float* __restrict__ out,
    float* __restrict__ ws)
{
    float* z     = ws;
    float* xcg   = z     + (size_t)B_ * ED * L_;
    float* delta = xcg   + (size_t)B_ * ED * L_;
    float* y     = delta + (size_t)B_ * ED * L_;
    float* Bm    = y     + (size_t)B_ * ED * L_;
    float* Cm    = Bm    + (size_t)B_ * L_ * NS;
    float* hA    = Cm    + (size_t)B_ * L_ * NS;
    float* hB    = hA    + (size_t)B_ * DM * L_;
    float* sumA  = hB    + (size_t)B_ * DM * L_;
    float* sumH  = sumA  + (size_t)B_ * ED * CH * NS;
    unsigned* bar = (unsigned*)(ws + WS_FLOATS);

    __shared__ float sh[DM][48];     // residual h, 47 positions (l0-15..l0+31)
    __shared__ float sxin[ED][48];   // xin (47 pos); also reused as y-staging
    __shared__ float sxc[ED][33];    // xc, 32 positions (+1 pad)
    __shared__ float srn[48];        // rms scale per position
    __shared__ float sdr[32];        // dt-rank scalar per position

    const int tid = threadIdx.x;

    for (int layer = 0; layer < NLAYERS; ++layer) {
        const float* ipw = in_proj_w + (size_t)layer * 96 * DM;
        const float* nw  = norm_w    + (size_t)layer * DM;
        const float* cw  = conv_w    + (size_t)layer * ED * DCONV;
        const float* cb  = conv_b    + (size_t)layer * ED;
        const float* xpw = x_proj_w  + (size_t)layer * 65 * ED;
        const float* dtw = dt_proj_w + (size_t)layer * ED;
        const float* dtb = dt_proj_b + (size_t)layer * ED;
        const float* al  = A_log     + (size_t)layer * ED * NS;
        const float* dpp = Dp        + (size_t)layer * ED;
        const float* ow  = (layer == 0) ? out_proj_w
                          : out_proj_w + (size_t)(layer - 1) * DM * ED;
        float* hout      = (layer & 1) ? hB : hA;
        const float* hin = (layer & 1) ? hA : hB;   // only read when layer>0

        // ================= PRE: one 32-pos tile per block ===================
        {
            const int b  = blockIdx.x >> 6;
            const int l0 = (blockIdx.x & 63) * 32;

            // Phase 1: residual h for 47 positions
            if (layer > 0) {
                // stage y tile (47 halo positions) into LDS (reuse sxin)
                for (int i = tid; i < ED * 47; i += 256) {
                    int e = i / 47, p = i % 47;
                    int l = l0 - 15 + p;
                    sxin[e][p] = (l >= 0)
                        ? y[((size_t)b * ED + e) * L_ + l] : 0.f;
                }
                __syncthreads();
                for (int i = tid; i < DM * 47; i += 256) {
                    int d = i / 47, p = i % 47;
                    int l = l0 - 15 + p;
                    float hv = 0.f;
                    if (l >= 0) {
                        hv = hin[((size_t)b * DM + d) * L_ + l];
                        const float* wp = ow + d * ED;
                        float acc = 0.f;
#pragma unroll
                        for (int e = 0; e < ED; ++e) acc += sxin[e][p] * wp[e];
                        hv += acc;
                        if (p >= 15 && layer < NLAYERS - 1)
                            hout[((size_t)b * DM + d) * L_ + l] = hv;
                    }
                    sh[d][p] = hv;
                }
            } else {
                // layer 0: h = x, materialized to hout for layer 1
                for (int i = tid; i < DM * 47; i += 256) {
                    int d = i / 47, p = i % 47;
                    int l = l0 - 15 + p;
                    float hv = 0.f;
                    if (l >= 0) {
                        hv = x[((size_t)b * L_ + l) * DM + d];
                        if (p >= 15)
                            hout[((size_t)b * DM + d) * L_ + l] = hv;
                    }
                    sh[d][p] = hv;
                }
            }
            __syncthreads();

            // Phase 2: rms scale per position
            if (tid < 47) {
                float ss = 0.f;
#pragma unroll
                for (int d = 0; d < DM; ++d) ss += sh[d][tid] * sh[d][tid];
                srn[tid] = rsqrtf(ss * (1.f / DM) + EPS);
            }
            __syncthreads();

            // Phase 3a: xin (47 positions, into LDS; overwrites y-staging)
            for (int i = tid; i < ED * 47; i += 256) {
                int e = i / 47, p = i % 47;
                const float* wp = ipw + e * DM;
                float acc = 0.f;
#pragma unroll
                for (int d = 0; d < DM; ++d) acc += sh[d][p] * nw[d] * wp[d];
                sxin[e][p] = acc * srn[p];
            }
            // Phase 3b: z (32 owned positions, to global)
            for (int i = tid; i < ED * 32; i += 256) {
                int e = i >> 5, po = i & 31;
                int p = po + 15;
                const float* wp = ipw + (ED + e) * DM;
                float acc = 0.f;
#pragma unroll
                for (int d = 0; d < DM; ++d) acc += sh[d][p] * nw[d] * wp[d];
                z[((size_t)b * ED + e) * L_ + l0 + po] = acc * srn[p];
            }
            __syncthreads();

            // Phase 4: conv + SiLU
            for (int i = tid; i < ED * 32; i += 256) {
                int e = i >> 5, po = i & 31;
                const float* wp = cw + e * DCONV;
                float acc = cb[e];
#pragma unroll
                for (int k = 0; k < DCONV; ++k) acc += sxin[e][po + k] * wp[k];
                float v = acc / (1.f + __expf(-acc));
                sxc[e][po] = v;
                xcg[((size_t)b * ED + e) * L_ + l0 + po] = v;
            }
            __syncthreads();

            // Phase 5: x_proj. og = 8 output-groups of 8 rows; li = position.
            {
                int og = tid >> 5, li = tid & 31;
                int isB = og < 4;
                int nb = isB ? og * 8 : (og - 4) * 8;
                int rowBase = isB ? (1 + nb) : (1 + NS + nb);
                const float* wr = xpw + rowBase * ED;
                float a0=0,a1=0,a2=0,a3=0,a4=0,a5=0,a6=0,a7=0, dr=0;
#pragma unroll 4
                for (int e = 0; e < ED; ++e) {
                    float xv = sxc[e][li];
                    a0 += xv * wr[0*ED+e]; a1 += xv * wr[1*ED+e];
                    a2 += xv * wr[2*ED+e]; a3 += xv * wr[3*ED+e];
                    a4 += xv * wr[4*ED+e]; a5 += xv * wr[5*ED+e];
                    a6 += xv * wr[6*ED+e]; a7 += xv * wr[7*ED+e];
                    dr += xv * xpw[e];
                }
                float* outp = (isB ? Bm : Cm) + ((size_t)(b * L_ + l0 + li)) * NS + nb;
                ((float4*)outp)[0] = make_float4(a0, a1, a2, a3);
                ((float4*)outp)[1] = make_float4(a4, a5, a6, a7);
                if (og == 0) sdr[li] = dr;
            }
            __syncthreads();

            // Phase 6: delta = softplus(dr*dtw + dtb)
            for (int i = tid; i < ED * 32; i += 256) {
                int e = i >> 5, po = i & 31;
                float s = sdr[po] * dtw[e] + dtb[e];
                delta[((size_t)b * ED + e) * L_ + l0 + po] =
                    fmaxf(s, 0.f) + log1pf(__expf(-fabsf(s)));
            }
        }
        grid_barrier(bar, layer * 3 + 0);

        // ================= SCAN1: per (b,e,n,chunk) local scan ==============
        for (int task = blockIdx.x; task < NSCANTASK; task += NBLK) {
            int t = task * 256 + tid;
            int n = t & 31;
            int g = t >> 5;                 // (b*ED+e)*CH + chunk
            int chunk = g & (CH - 1);
            int be    = g >> 5;             // CH == 32
            int e = be % ED;
            int b = be / ED;
            float A = -__expf(al[e * NS + n]);
            size_t eRow = (size_t)(b * ED + e) * L_ + chunk * CL;
            const float4* dRow = (const float4*)(delta + eRow);
            const float4* xRow = (const float4*)(xcg + eRow);
            const float* bBase = Bm + ((size_t)b * L_ + chunk * CL) * NS + n;
            float h = 0.f, sd = 0.f;
#pragma unroll 4
            for (int q = 0; q < CL / 4; ++q) {
                float4 d4 = dRow[q];
                float4 x4 = xRow[q];
                float b0 = bBase[(4 * q + 0) * NS];
                float b1 = bBase[(4 * q + 1) * NS];
                float b2 = bBase[(4 * q + 2) * NS];
                float b3 = bBase[(4 * q + 3) * NS];
                h = __expf(d4.x * A) * h + (d4.x * x4.x) * b0;
                h = __expf(d4.y * A) * h + (d4.y * x4.y) * b1;
                h = __expf(d4.z * A) * h + (d4.z * x4.z) * b2;
                h = __expf(d4.w * A) * h + (d4.w * x4.w) * b3;
                sd += d4.x + d4.y + d4.z + d4.w;
            }
            sumA[g * NS + n] = __expf(A * sd);
            sumH[g * NS + n] = h;
        }
        grid_barrier(bar, layer * 3 + 1);

        // ================= SCAN3: prefix fold + rescan + gate ===============
        for (int task = blockIdx.x; task < NSCANTASK; task += NBLK) {
            int t = task * 256 + tid;
            int n = t & 31;
            int g = t >> 5;
            int chunk = g & (CH - 1);
            int be    = g >> 5;
            int e = be % ED;
            int b = be / ED;
            float A  = -__expf(al[e * NS + n]);
            float Dv = dpp[e];

            // inline exclusive prefix over this chain's earlier chunk summaries
            float h = 0.f;
            int base = be * CH;
            for (int c = 0; c < chunk; ++c) {
                int idx = (base + c) * NS + n;
                h = sumA[idx] * h + sumH[idx];
            }

            size_t eRow = (size_t)(b * ED + e) * L_ + chunk * CL;
            size_t nRow = ((size_t)b * L_ + chunk * CL) * NS + n;
            const float4* dRow = (const float4*)(delta + eRow);
            const float4* xRow = (const float4*)(xcg + eRow);
            const float* bBase = Bm + nRow;
            const float* cBase = Cm + nRow;
            const float* zRow  = z + eRow;
            float*       yRow  = y + eRow;
            int s0 = n & 1, s1 = n & 2;
            for (int q = 0; q < CL / 4; ++q) {
                float4 d4 = dRow[q];
                float4 x4 = xRow[q];
                float bb0 = bBase[(4 * q + 0) * NS];
                float bb1 = bBase[(4 * q + 1) * NS];
                float bb2 = bBase[(4 * q + 2) * NS];
                float bb3 = bBase[(4 * q + 3) * NS];
                float cc0 = cBase[(4 * q + 0) * NS];
                float cc1 = cBase[(4 * q + 1) * NS];
                float cc2 = cBase[(4 * q + 2) * NS];
                float cc3 = cBase[(4 * q + 3) * NS];
                h = __expf(d4.x * A) * h + (d4.x * x4.x) * bb0;  float p0 = h * cc0;
                h = __expf(d4.y * A) * h + (d4.y * x4.y) * bb1;  float p1 = h * cc1;
                h = __expf(d4.z * A) * h + (d4.z * x4.z) * bb2;  float p2 = h * cc2;
                h = __expf(d4.w * A) * h + (d4.w * x4.w) * bb3;  float p3 = h * cc3;
                // multi-value butterfly: lane%4==k ends with sum over 32 lanes of p_k
                float u  = s0 ? p1 : p0;
                float us = s0 ? p0 : p1;
                u += __shfl_xor(us, 1, 32);
                float v  = s0 ? p3 : p2;
                float vs = s0 ? p2 : p3;
                v += __shfl_xor(vs, 1, 32);
                float wv  = s1 ? v : u;
                float wvs = s1 ? u : v;
                wv += __shfl_xor(wvs, 2, 32);
                wv += __shfl_xor(wv, 4, 32);
                wv += __shfl_xor(wv, 8, 32);
                wv += __shfl_xor(wv, 16, 32);
                if (n < 4) {
                    int l4 = q * 4;
                    float xs = (n == 0) ? x4.x : (n == 1) ? x4.y : (n == 2) ? x4.z : x4.w;
                    float yr = wv + Dv * xs;
                    float zv = zRow[l4 + n];
                    yRow[l4 + n] = yr * (zv / (1.f + __expf(-zv)));
                }
            }
        }
        grid_barrier(bar, layer * 3 + 2);
    }

    // ================= classifier on last token =============================
    if (blockIdx.x == 0 && tid < B_ * NCLASSES) {
        int b = tid / NCLASSES;
        int c = tid - b * NCLASSES;
        const float* yp = y + (size_t)b * ED * L_ + (L_ - 1);
        const float* wp = fc_w + c * ED;
        float acc = fc_b[c];
#pragma unroll
        for (int e = 0; e < ED; ++e) acc += yp[(size_t)e * L_] * wp[e];
        out[tid] = acc;
    }
}

// ---------------------------------------------------------------------------
extern "C" void kernel_launch(void* const* d_in, const int* in_sizes, int n_in,
                              void* d_out, int out_size, void* d_ws, size_t ws_size,
                              hipStream_t stream)
{
    const float* x          = (const float*)d_in[0];
    const float* in_proj_w  = (const float*)d_in[1];
    const float* conv_w     = (const float*)d_in[2];
    const float* conv_b     = (const float*)d_in[3];
    const float* x_proj_w   = (const float*)d_in[4];
    const float* dt_proj_w  = (const float*)d_in[5];
    const float* dt_proj_b  = (const float*)d_in[6];
    const float* A_log      = (const float*)d_in[7];
    const float* Dp         = (const float*)d_in[8];
    const float* out_proj_w = (const float*)d_in[9];
    const float* norm_w     = (const float*)d_in[10];
    const float* fc_w       = (const float*)d_in[11];
    const float* fc_b       = (const float*)d_in[12];
    float* ws = (float*)d_ws;

    // zero the barrier counters (graph-capturable memset node)
    hipMemsetAsync((void*)(ws + WS_FLOATS), 0, BAR_BYTES, stream);

    k_all<<<dim3(NBLK), dim3(256), 0, stream>>>(
        x, in_proj_w, conv_w, conv_b, x_proj_w, dt_proj_w, dt_proj_b,
        A_log, Dp, out_proj_w, norm_w, fc_w, fc_b, (float*)d_out, ws);
}

// Round 4
// 658.677 us; speedup vs baseline: 1.5148x; 1.5148x over previous
//
#include <hip/hip_runtime.h>
#include <math.h>

#define B_ 8
#define L_ 2048
#define DM 6
#define ED 48
#define NS 32
#define DCONV 16
#define NLAYERS 4
#define NCLASSES 4
#define EPS 1e-5f

#define NBLK 512           // == #PRE tiles; 2 blocks/CU guaranteed co-resident
#define NCHAIN (B_ * ED)   // 384 scan chains, one block each
#define SPAN 256           // L_/8: contiguous steps per 32-lane group

// workspace: buffers + barrier area (offsets unchanged from prev round)
#define WS_FLOATS 5177344
#define BAR_EPOCHS 8
#define BAR_SLOT_U32 16            // 64B padding per counter
#define BAR_SLOTS 9                // 8 leaves + 1 master per epoch
#define BAR_BYTES (BAR_EPOCHS * BAR_SLOTS * BAR_SLOT_U32 * 4)

// Grid barrier, v2. Round-3 profile: 66us/barrier, VALUBusy 13% -> the
// ACQUIRE-scoped spin load was issuing cache-maintenance ops every
// iteration from 512 waves (FETCH/WRITE counters showed full workspace
// flush+refetch per layer). Fix: RELAXED spin (no cache ops), exactly one
// release fence before arrival and one acquire fence after exit.
// Monotone per-epoch counters: no reset, no sense reversal.
__device__ __forceinline__ void grid_barrier(unsigned* bar, int epoch)
{
    __syncthreads();
    if (threadIdx.x == 0) {
        unsigned* leaf   = bar + (epoch * BAR_SLOTS + (blockIdx.x & 7)) * BAR_SLOT_U32;
        unsigned* master = bar + (epoch * BAR_SLOTS + 8) * BAR_SLOT_U32;
        __threadfence();                       // release: flush dirty L2 once
        if (atomicAdd(leaf, 1u) == (NBLK / 8) - 1)
            atomicAdd(master, 1u);             // last arrival of this leaf
        while (__hip_atomic_load(master, __ATOMIC_RELAXED,
                                 __HIP_MEMORY_SCOPE_AGENT) < 8u)
            __builtin_amdgcn_s_sleep(2);
        __threadfence();                       // acquire: invalidate once
    }
    __syncthreads();
}

// Layouts:
//   h, z, xc, delta, y : [b][feat][l]   (l contiguous)
//   Bm, Cm             : [b][l][n]      (n contiguous)
__global__ void __launch_bounds__(256, 2) k_all(
    const float* __restrict__ x,
    const float* __restrict__ in_proj_w,
    const float* __restrict__ conv_w,
    const float* __restrict__ conv_b,
    const float* __restrict__ x_proj_w,
    const float* __restrict__ dt_proj_w,
    const float* __restrict__ dt_proj_b,
    const float* __restrict__ A_log,
    const float* __restrict__ Dp,
    const float* __restrict__ out_proj_w,
    const float* __restrict__ norm_w,
    const float* __restrict__ fc_w,
    const float* __restrict__ fc_b,
    float* __restrict__ out,
    float* __restrict__ ws)
{
    float* z     = ws;
    float* xcg   = z     + (size_t)B_ * ED * L_;
    float* delta = xcg   + (size_t)B_ * ED * L_;
    float* y     = delta + (size_t)B_ * ED * L_;
    float* Bm    = y     + (size_t)B_ * ED * L_;
    float* Cm    = Bm    + (size_t)B_ * L_ * NS;
    float* hA    = Cm    + (size_t)B_ * L_ * NS;
    float* hB    = hA    + (size_t)B_ * DM * L_;
    unsigned* bar = (unsigned*)(ws + WS_FLOATS);

    __shared__ float sh[DM][48];     // residual h, 47 positions (l0-15..l0+31)
    __shared__ float sxin[ED][48];   // xin (47 pos); also reused as y-staging
    __shared__ float sxc[ED][33];    // xc, 32 positions (+1 pad)
    __shared__ float srn[48];        // rms scale per position
    __shared__ float sdr[32];        // dt-rank scalar per position
    __shared__ float sA[8][32];      // scan span summaries: exp(A*sum d)
    __shared__ float sH[8][32];      // scan span summaries: local end h

    const int tid = threadIdx.x;

    for (int layer = 0; layer < NLAYERS; ++layer) {
        const float* ipw = in_proj_w + (size_t)layer * 96 * DM;
        const float* nw  = norm_w    + (size_t)layer * DM;
        const float* cw  = conv_w    + (size_t)layer * ED * DCONV;
        const float* cb  = conv_b    + (size_t)layer * ED;
        const float* xpw = x_proj_w  + (size_t)layer * 65 * ED;
        const float* dtw = dt_proj_w + (size_t)layer * ED;
        const float* dtb = dt_proj_b + (size_t)layer * ED;
        const float* al  = A_log     + (size_t)layer * ED * NS;
        const float* dpp = Dp        + (size_t)layer * ED;
        const float* ow  = (layer == 0) ? out_proj_w
                          : out_proj_w + (size_t)(layer - 1) * DM * ED;
        float* hout      = (layer & 1) ? hB : hA;
        const float* hin = (layer & 1) ? hA : hB;   // only read when layer>0

        // ================= PRE: one 32-pos tile per block ===================
        {
            const int b  = blockIdx.x >> 6;
            const int l0 = (blockIdx.x & 63) * 32;

            // Phase 1: residual h for 47 positions
            if (layer > 0) {
                // stage y tile (47 halo positions) into LDS (reuse sxin)
                for (int i = tid; i < ED * 47; i += 256) {
                    int e = i / 47, p = i % 47;
                    int l = l0 - 15 + p;
                    sxin[e][p] = (l >= 0)
                        ? y[((size_t)b * ED + e) * L_ + l] : 0.f;
                }
                __syncthreads();
                for (int i = tid; i < DM * 47; i += 256) {
                    int d = i / 47, p = i % 47;
                    int l = l0 - 15 + p;
                    float hv = 0.f;
                    if (l >= 0) {
                        hv = hin[((size_t)b * DM + d) * L_ + l];
                        const float* wp = ow + d * ED;
                        float acc = 0.f;
#pragma unroll
                        for (int e = 0; e < ED; ++e) acc += sxin[e][p] * wp[e];
                        hv += acc;
                        if (p >= 15 && layer < NLAYERS - 1)
                            hout[((size_t)b * DM + d) * L_ + l] = hv;
                    }
                    sh[d][p] = hv;
                }
            } else {
                // layer 0: h = x, materialized to hout for layer 1
                for (int i = tid; i < DM * 47; i += 256) {
                    int d = i / 47, p = i % 47;
                    int l = l0 - 15 + p;
                    float hv = 0.f;
                    if (l >= 0) {
                        hv = x[((size_t)b * L_ + l) * DM + d];
                        if (p >= 15)
                            hout[((size_t)b * DM + d) * L_ + l] = hv;
                    }
                    sh[d][p] = hv;
                }
            }
            __syncthreads();

            // Phase 2: rms scale per position
            if (tid < 47) {
                float ss = 0.f;
#pragma unroll
                for (int d = 0; d < DM; ++d) ss += sh[d][tid] * sh[d][tid];
                srn[tid] = rsqrtf(ss * (1.f / DM) + EPS);
            }
            __syncthreads();

            // Phase 3a: xin (47 positions, into LDS; overwrites y-staging)
            for (int i = tid; i < ED * 47; i += 256) {
                int e = i / 47, p = i % 47;
                const float* wp = ipw + e * DM;
                float acc = 0.f;
#pragma unroll
                for (int d = 0; d < DM; ++d) acc += sh[d][p] * nw[d] * wp[d];
                sxin[e][p] = acc * srn[p];
            }
            // Phase 3b: z (32 owned positions, to global)
            for (int i = tid; i < ED * 32; i += 256) {
                int e = i >> 5, po = i & 31;
                int p = po + 15;
                const float* wp = ipw + (ED + e) * DM;
                float acc = 0.f;
#pragma unroll
                for (int d = 0; d < DM; ++d) acc += sh[d][p] * nw[d] * wp[d];
                z[((size_t)b * ED + e) * L_ + l0 + po] = acc * srn[p];
            }
            __syncthreads();

            // Phase 4: conv + SiLU
            for (int i = tid; i < ED * 32; i += 256) {
                int e = i >> 5, po = i & 31;
                const float* wp = cw + e * DCONV;
                float acc = cb[e];
#pragma unroll
                for (int k = 0; k < DCONV; ++k) acc += sxin[e][po + k] * wp[k];
                float v = acc / (1.f + __expf(-acc));
                sxc[e][po] = v;
                xcg[((size_t)b * ED + e) * L_ + l0 + po] = v;
            }
            __syncthreads();

            // Phase 5: x_proj. og = 8 output-groups of 8 rows; li = position.
            {
                int og = tid >> 5, li = tid & 31;
                int isB = og < 4;
                int nb = isB ? og * 8 : (og - 4) * 8;
                int rowBase = isB ? (1 + nb) : (1 + NS + nb);
                const float* wr = xpw + rowBase * ED;
                float a0=0,a1=0,a2=0,a3=0,a4=0,a5=0,a6=0,a7=0, dr=0;
#pragma unroll 4
                for (int e = 0; e < ED; ++e) {
                    float xv = sxc[e][li];
                    a0 += xv * wr[0*ED+e]; a1 += xv * wr[1*ED+e];
                    a2 += xv * wr[2*ED+e]; a3 += xv * wr[3*ED+e];
                    a4 += xv * wr[4*ED+e]; a5 += xv * wr[5*ED+e];
                    a6 += xv * wr[6*ED+e]; a7 += xv * wr[7*ED+e];
                    dr += xv * xpw[e];
                }
                float* outp = (isB ? Bm : Cm) + ((size_t)(b * L_ + l0 + li)) * NS + nb;
                ((float4*)outp)[0] = make_float4(a0, a1, a2, a3);
                ((float4*)outp)[1] = make_float4(a4, a5, a6, a7);
                if (og == 0) sdr[li] = dr;
            }
            __syncthreads();

            // Phase 6: delta = softplus(dr*dtw + dtb)
            for (int i = tid; i < ED * 32; i += 256) {
                int e = i >> 5, po = i & 31;
                float s = sdr[po] * dtw[e] + dtb[e];
                delta[((size_t)b * ED + e) * L_ + l0 + po] =
                    fmaxf(s, 0.f) + log1pf(__expf(-fabsf(s)));
            }
        }
        grid_barrier(bar, layer * 2 + 0);

        // ================= SCAN: one chain (b,e) per block ==================
        // 8 groups x 32 lanes; group gid owns contiguous steps
        // [gid*SPAN, (gid+1)*SPAN). Pass 1: local scan from h=0 + span
        // summary to LDS. Pass 2: fold <=7 span prefixes, rescan + gate.
        // Replaces the old SCAN1/SCAN3 pair (one barrier + sumA/sumH
        // round-trip + one duplicate input read eliminated).
        if (blockIdx.x < NCHAIN) {
            const int e   = blockIdx.x % ED;
            const int b   = blockIdx.x / ED;
            const int gid = tid >> 5;
            const int n   = tid & 31;
            const float A  = -__expf(al[e * NS + n]);
            const float Dv = dpp[e];

            size_t eRow = (size_t)(b * ED + e) * L_ + gid * SPAN;
            size_t nRow = ((size_t)b * L_ + gid * SPAN) * NS + n;
            const float4* dRow = (const float4*)(delta + eRow);
            const float4* xRow = (const float4*)(xcg + eRow);
            const float* bBase = Bm + nRow;
            const float* cBase = Cm + nRow;
            const float* zRow  = z + eRow;
            float*       yRow  = y + eRow;

            // Pass 1: local scan from h=0, telescoped decay via sum(d)
            float h = 0.f, sd = 0.f;
#pragma unroll 4
            for (int q = 0; q < SPAN / 4; ++q) {
                float4 d4 = dRow[q];
                float4 x4 = xRow[q];
                float b0 = bBase[(4 * q + 0) * NS];
                float b1 = bBase[(4 * q + 1) * NS];
                float b2 = bBase[(4 * q + 2) * NS];
                float b3 = bBase[(4 * q + 3) * NS];
                h = __expf(d4.x * A) * h + (d4.x * x4.x) * b0;
                h = __expf(d4.y * A) * h + (d4.y * x4.y) * b1;
                h = __expf(d4.z * A) * h + (d4.z * x4.z) * b2;
                h = __expf(d4.w * A) * h + (d4.w * x4.w) * b3;
                sd += d4.x + d4.y + d4.z + d4.w;
            }
            sA[gid][n] = __expf(A * sd);
            sH[gid][n] = h;
            __syncthreads();

            // prefix over earlier spans (<=7 LDS folds)
            h = 0.f;
            for (int s = 0; s < gid; ++s)
                h = sA[s][n] * h + sH[s][n];

            // Pass 2: rescan with correct prefix, reduce over n, gate, store
            int s0 = n & 1, s1 = n & 2;
            for (int q = 0; q < SPAN / 4; ++q) {
                float4 d4 = dRow[q];
                float4 x4 = xRow[q];
                float bb0 = bBase[(4 * q + 0) * NS];
                float bb1 = bBase[(4 * q + 1) * NS];
                float bb2 = bBase[(4 * q + 2) * NS];
                float bb3 = bBase[(4 * q + 3) * NS];
                float cc0 = cBase[(4 * q + 0) * NS];
                float cc1 = cBase[(4 * q + 1) * NS];
                float cc2 = cBase[(4 * q + 2) * NS];
                float cc3 = cBase[(4 * q + 3) * NS];
                h = __expf(d4.x * A) * h + (d4.x * x4.x) * bb0;  float p0 = h * cc0;
                h = __expf(d4.y * A) * h + (d4.y * x4.y) * bb1;  float p1 = h * cc1;
                h = __expf(d4.z * A) * h + (d4.z * x4.z) * bb2;  float p2 = h * cc2;
                h = __expf(d4.w * A) * h + (d4.w * x4.w) * bb3;  float p3 = h * cc3;
                // multi-value butterfly: lane%4==k ends with sum over 32 lanes of p_k
                float u  = s0 ? p1 : p0;
                float us = s0 ? p0 : p1;
                u += __shfl_xor(us, 1, 32);
                float v  = s0 ? p3 : p2;
                float vs = s0 ? p2 : p3;
                v += __shfl_xor(vs, 1, 32);
                float wv  = s1 ? v : u;
                float wvs = s1 ? u : v;
                wv += __shfl_xor(wvs, 2, 32);
                wv += __shfl_xor(wv, 4, 32);
                wv += __shfl_xor(wv, 8, 32);
                wv += __shfl_xor(wv, 16, 32);
                if (n < 4) {
                    int l4 = q * 4;
                    float xs = (n == 0) ? x4.x : (n == 1) ? x4.y : (n == 2) ? x4.z : x4.w;
                    float yr = wv + Dv * xs;
                    float zv = zRow[l4 + n];
                    yRow[l4 + n] = yr * (zv / (1.f + __expf(-zv)));
                }
            }
            __syncthreads();   // sA/sH quiescent before next layer reuses LDS
        }
        grid_barrier(bar, layer * 2 + 1);
    }

    // ================= classifier on last token =============================
    if (blockIdx.x == 0 && tid < B_ * NCLASSES) {
        int b = tid / NCLASSES;
        int c = tid - b * NCLASSES;
        const float* yp = y + (size_t)b * ED * L_ + (L_ - 1);
        const float* wp = fc_w + c * ED;
        float acc = fc_b[c];
#pragma unroll
        for (int e = 0; e < ED; ++e) acc += yp[(size_t)e * L_] * wp[e];
        out[tid] = acc;
    }
}

// ---------------------------------------------------------------------------
extern "C" void kernel_launch(void* const* d_in, const int* in_sizes, int n_in,
                              void* d_out, int out_size, void* d_ws, size_t ws_size,
                              hipStream_t stream)
{
    const float* x          = (const float*)d_in[0];
    const float* in_proj_w  = (const float*)d_in[1];
    const float* conv_w     = (const float*)d_in[2];
    const float* conv_b     = (const float*)d_in[3];
    const float* x_proj_w   = (const float*)d_in[4];
    const float* dt_proj_w  = (const float*)d_in[5];
    const float* dt_proj_b  = (const float*)d_in[6];
    const float* A_log      = (const float*)d_in[7];
    const float* Dp         = (const float*)d_in[8];
    const float* out_proj_w = (const float*)d_in[9];
    const float* norm_w     = (const float*)d_in[10];
    const float* fc_w       = (const float*)d_in[11];
    const float* fc_b       = (const float*)d_in[12];
    float* ws = (float*)d_ws;

    // zero the barrier counters (graph-capturable memset node)
    hipMemsetAsync((void*)(ws + WS_FLOATS), 0, BAR_BYTES, stream);

    k_all<<<dim3(NBLK), dim3(256), 0, stream>>>(
        x, in_proj_w, conv_w, conv_b, x_proj_w, dt_proj_w, dt_proj_b,
        A_log, Dp, out_proj_w, norm_w, fc_w, fc_b, (float*)d_out, ws);
}

// Round 5
// 514.883 us; speedup vs baseline: 1.9378x; 1.2793x over previous
//
#include <hip/hip_runtime.h>
#include <math.h>

#define B_ 8
#define L_ 2048
#define DM 6
#define ED 48
#define NS 32
#define DCONV 16
#define NLAYERS 4
#define NCLASSES 4
#define EPS 1e-5f

#define NBLK 512           // 2 blocks/CU co-resident (persistent)
#define EDL (B_ * ED * L_)     // 786432 floats
#define NSL (B_ * L_ * NS)     // 524288
#define DML (B_ * DM * L_)     // 98304

// Per-layer buffer instances (WRITE-ONCE per execution -> no stale-L1 hazard
// without any cache maintenance; see barrier design below).
// layout per layer: z, xc, delta, y, Bm, Cm, h
#define LSTRIDE (4 * EDL + 2 * NSL + DML)   // 4,292,608 floats/layer
#define WS_BAR (NLAYERS * LSTRIDE)          // float offset of barrier area (~66 MB < 256 MB ws)

// barrier area (u32): reg[8][16] | gcnt[16] | bar[9 groups][8 epochs][16]
#define BAR_U32 (8 * 16 + 16 + 9 * 8 * 16)
#define BAR_BYTES (BAR_U32 * 4)

// ---------------------------------------------------------------------------
// Design (round-5): batch b -> XCD b. All producer/consumer traffic for a
// batch stays inside one XCD's L2 (write-through L1 -> L2 is the coherence
// point). Barriers are per-XCD counters in L3 via RELAXED agent atomics:
// NO buffer_wbl2 / buffer_inv anywhere (round 3/4 showed ~70us/barrier from
// 512x agent fences + full-L2 dump refetch). Stale-L1 is impossible because
// every buffer address is written exactly once per execution (per-layer
// instances) and read only after the barrier; L1 lines are cold on first
// read (kernel-entry acquire invalidated them).
// Fallback: if registration doesn't see exactly 8 XCDs, all blocks form one
// global group and barriers use full __threadfence (round-4 semantics).
// ---------------------------------------------------------------------------

__global__ void __launch_bounds__(256, 2) k_all(
    const float* __restrict__ x,
    const float* __restrict__ in_proj_w,
    const float* __restrict__ conv_w,
    const float* __restrict__ conv_b,
    const float* __restrict__ x_proj_w,
    const float* __restrict__ dt_proj_w,
    const float* __restrict__ dt_proj_b,
    const float* __restrict__ A_log,
    const float* __restrict__ Dp,
    const float* __restrict__ out_proj_w,
    const float* __restrict__ norm_w,
    const float* __restrict__ fc_w,
    const float* __restrict__ fc_b,
    float* __restrict__ out,
    float* __restrict__ ws)
{
    unsigned* ureg = (unsigned*)(ws + WS_BAR);   // [8][16] per-XCD block counts
    unsigned* gcnt = ureg + 8 * 16;              // [16] global registration
    unsigned* bar  = gcnt + 16;                  // [9][8][16] group x epoch

    __shared__ float sh[DM][48];     // residual h, 47 positions (l0-15..l0+31)
    __shared__ float sxin[ED][48];   // xin (47 pos); also reused as y-staging
    __shared__ float sxc[ED][33];    // xc, 32 positions (+1 pad)
    __shared__ float srn[48];        // rms scale per position
    __shared__ float sdr[32];        // dt-rank scalar per position
    __shared__ float sA[8][32];      // scan span summaries: exp(A*sum d)
    __shared__ float sH[8][32];      // scan span summaries: local end h
    __shared__ int s_xcd, s_lidx, s_n, s_mode;

    const int tid = threadIdx.x;

    // ---------------- registration: discover block->XCD mapping ------------
    if (tid == 0) {
        unsigned xcd;
        asm volatile("s_getreg_b32 %0, hwreg(HW_REG_XCC_ID)" : "=s"(xcd));
        xcd &= 7u;
        int lidx = (int)__hip_atomic_fetch_add(&ureg[xcd * 16], 1u,
                        __ATOMIC_RELAXED, __HIP_MEMORY_SCOPE_AGENT);
        __hip_atomic_fetch_add(&gcnt[0], 1u,
                        __ATOMIC_RELAXED, __HIP_MEMORY_SCOPE_AGENT);
        while (__hip_atomic_load(&gcnt[0], __ATOMIC_RELAXED,
                                 __HIP_MEMORY_SCOPE_AGENT) < (unsigned)NBLK)
            __builtin_amdgcn_s_sleep(1);
        int npres = 0;
        for (int xx = 0; xx < 8; ++xx) {
            unsigned c = __hip_atomic_load(&ureg[xx * 16], __ATOMIC_RELAXED,
                                           __HIP_MEMORY_SCOPE_AGENT);
            if (c) npres++;
        }
        unsigned nm = __hip_atomic_load(&ureg[xcd * 16], __ATOMIC_RELAXED,
                                        __HIP_MEMORY_SCOPE_AGENT);
        s_xcd = (int)xcd; s_lidx = lidx; s_n = (int)nm;
        s_mode = (npres == 8) ? 0 : 1;
    }
    __syncthreads();

    const int  mode  = s_mode;                       // 0 = XCD-local, 1 = fallback
    const int  grp   = mode ? 8 : s_xcd;             // barrier group id
    const unsigned gsz = mode ? (unsigned)NBLK : (unsigned)s_n;
    const int  lidx  = mode ? (int)blockIdx.x : s_lidx;
    const int  nwork = mode ? NBLK : s_n;
    const int  b0    = mode ? 0 : s_xcd;             // batches this group owns
    const int  bN    = mode ? B_ : s_xcd + 1;

    // group barrier: counters only (normal mode); full fences in fallback
    auto gbar = [&](int epoch) {
        __syncthreads();
        if (tid == 0) {
            unsigned* c = &bar[(grp * 8 + epoch) * 16];
            if (mode) __threadfence();
            asm volatile("" ::: "memory");
            __hip_atomic_fetch_add(c, 1u, __ATOMIC_RELAXED,
                                   __HIP_MEMORY_SCOPE_AGENT);
            while (__hip_atomic_load(c, __ATOMIC_RELAXED,
                                     __HIP_MEMORY_SCOPE_AGENT) < gsz)
                __builtin_amdgcn_s_sleep(2);
            asm volatile("" ::: "memory");
            if (mode) __threadfence();
        }
        __syncthreads();
    };

    for (int layer = 0; layer < NLAYERS; ++layer) {
        const float* ipw = in_proj_w + (size_t)layer * 96 * DM;
        const float* nw  = norm_w    + (size_t)layer * DM;
        const float* cw  = conv_w    + (size_t)layer * ED * DCONV;
        const float* cb  = conv_b    + (size_t)layer * ED;
        const float* xpw = x_proj_w  + (size_t)layer * 65 * ED;
        const float* dtw = dt_proj_w + (size_t)layer * ED;
        const float* dtb = dt_proj_b + (size_t)layer * ED;
        const float* al  = A_log     + (size_t)layer * ED * NS;
        const float* dpp = Dp        + (size_t)layer * ED;
        const float* ow  = (layer == 0) ? out_proj_w
                          : out_proj_w + (size_t)(layer - 1) * DM * ED;

        float* Lb    = ws + (size_t)layer * LSTRIDE;
        float* zL    = Lb;
        float* xcL   = zL  + EDL;
        float* dL    = xcL + EDL;
        float* yL    = dL  + EDL;
        float* BmL   = yL  + EDL;
        float* CmL   = BmL + NSL;
        float* hL    = CmL + NSL;                    // h written by this layer
        const float* hprev = (layer > 0) ? (ws + (size_t)(layer-1) * LSTRIDE
                                            + 4 * EDL + 2 * NSL) : nullptr;
        const float* yprev = (layer > 0) ? (ws + (size_t)(layer-1) * LSTRIDE
                                            + 3 * EDL) : nullptr;

        // ================= PRE: 64 tiles per batch =========================
        for (int bb = b0; bb < bN; ++bb) {
            for (int t = lidx; t < 64; t += nwork) {
                const int b  = bb;
                const int l0 = t * 32;

                // Phase 1: residual h for 47 positions
                if (layer > 0) {
                    for (int i = tid; i < ED * 47; i += 256) {
                        int e = i / 47, p = i % 47;
                        int l = l0 - 15 + p;
                        sxin[e][p] = (l >= 0)
                            ? yprev[((size_t)b * ED + e) * L_ + l] : 0.f;
                    }
                    __syncthreads();
                    for (int i = tid; i < DM * 47; i += 256) {
                        int d = i / 47, p = i % 47;
                        int l = l0 - 15 + p;
                        float hv = 0.f;
                        if (l >= 0) {
                            hv = hprev[((size_t)b * DM + d) * L_ + l];
                            const float* wp = ow + d * ED;
                            float acc = 0.f;
#pragma unroll
                            for (int e = 0; e < ED; ++e) acc += sxin[e][p] * wp[e];
                            hv += acc;
                            if (p >= 15 && layer < NLAYERS - 1)
                                hL[((size_t)b * DM + d) * L_ + l] = hv;
                        }
                        sh[d][p] = hv;
                    }
                } else {
                    for (int i = tid; i < DM * 47; i += 256) {
                        int d = i / 47, p = i % 47;
                        int l = l0 - 15 + p;
                        float hv = 0.f;
                        if (l >= 0) {
                            hv = x[((size_t)b * L_ + l) * DM + d];
                            if (p >= 15)
                                hL[((size_t)b * DM + d) * L_ + l] = hv;
                        }
                        sh[d][p] = hv;
                    }
                }
                __syncthreads();

                // Phase 2: rms scale per position
                if (tid < 47) {
                    float ss = 0.f;
#pragma unroll
                    for (int d = 0; d < DM; ++d) ss += sh[d][tid] * sh[d][tid];
                    srn[tid] = rsqrtf(ss * (1.f / DM) + EPS);
                }
                __syncthreads();

                // Phase 3a: xin (47 positions, into LDS)
                for (int i = tid; i < ED * 47; i += 256) {
                    int e = i / 47, p = i % 47;
                    const float* wp = ipw + e * DM;
                    float acc = 0.f;
#pragma unroll
                    for (int d = 0; d < DM; ++d) acc += sh[d][p] * nw[d] * wp[d];
                    sxin[e][p] = acc * srn[p];
                }
                // Phase 3b: z (32 owned positions, to global)
                for (int i = tid; i < ED * 32; i += 256) {
                    int e = i >> 5, po = i & 31;
                    int p = po + 15;
                    const float* wp = ipw + (ED + e) * DM;
                    float acc = 0.f;
#pragma unroll
                    for (int d = 0; d < DM; ++d) acc += sh[d][p] * nw[d] * wp[d];
                    zL[((size_t)b * ED + e) * L_ + l0 + po] = acc * srn[p];
                }
                __syncthreads();

                // Phase 4: conv + SiLU
                for (int i = tid; i < ED * 32; i += 256) {
                    int e = i >> 5, po = i & 31;
                    const float* wp = cw + e * DCONV;
                    float acc = cb[e];
#pragma unroll
                    for (int k = 0; k < DCONV; ++k) acc += sxin[e][po + k] * wp[k];
                    float v = acc / (1.f + __expf(-acc));
                    sxc[e][po] = v;
                    xcL[((size_t)b * ED + e) * L_ + l0 + po] = v;
                }
                __syncthreads();

                // Phase 5: x_proj
                {
                    int og = tid >> 5, li = tid & 31;
                    int isB = og < 4;
                    int nb = isB ? og * 8 : (og - 4) * 8;
                    int rowBase = isB ? (1 + nb) : (1 + NS + nb);
                    const float* wr = xpw + rowBase * ED;
                    float a0=0,a1=0,a2=0,a3=0,a4=0,a5=0,a6=0,a7=0, dr=0;
#pragma unroll 4
                    for (int e = 0; e < ED; ++e) {
                        float xv = sxc[e][li];
                        a0 += xv * wr[0*ED+e]; a1 += xv * wr[1*ED+e];
                        a2 += xv * wr[2*ED+e]; a3 += xv * wr[3*ED+e];
                        a4 += xv * wr[4*ED+e]; a5 += xv * wr[5*ED+e];
                        a6 += xv * wr[6*ED+e]; a7 += xv * wr[7*ED+e];
                        dr += xv * xpw[e];
                    }
                    float* outp = (isB ? BmL : CmL)
                                + ((size_t)(b * L_ + l0 + li)) * NS + nb;
                    ((float4*)outp)[0] = make_float4(a0, a1, a2, a3);
                    ((float4*)outp)[1] = make_float4(a4, a5, a6, a7);
                    if (og == 0) sdr[li] = dr;
                }
                __syncthreads();

                // Phase 6: delta = softplus(dr*dtw + dtb)
                for (int i = tid; i < ED * 32; i += 256) {
                    int e = i >> 5, po = i & 31;
                    float s = sdr[po] * dtw[e] + dtb[e];
                    dL[((size_t)b * ED + e) * L_ + l0 + po] =
                        fmaxf(s, 0.f) + log1pf(__expf(-fabsf(s)));
                }
                __syncthreads();   // LDS quiescent before next tile
            }
        }
        gbar(layer * 2 + 0);

        // ================= SCAN: one chain (b,e) per block-iteration ========
        for (int bb = b0; bb < bN; ++bb) {
            for (int ch = lidx; ch < ED; ch += nwork) {
                const int e   = ch;
                const int b   = bb;
                const int gid = tid >> 5;
                const int n   = tid & 31;
                const float A  = -__expf(al[e * NS + n]);
                const float Dv = dpp[e];

                size_t eRow = (size_t)(b * ED + e) * L_ + gid * 256;
                size_t nRow = ((size_t)b * L_ + gid * 256) * NS + n;
                const float4* dRow = (const float4*)(dL + eRow);
                const float4* xRow = (const float4*)(xcL + eRow);
                const float* bBase = BmL + nRow;
                const float* cBase = CmL + nRow;
                const float* zRow  = zL + eRow;
                float*       yRow  = yL + eRow;

                // Pass 1: local scan from h=0, telescoped decay via sum(d)
                float h = 0.f, sd = 0.f;
#pragma unroll 4
                for (int q = 0; q < 64; ++q) {
                    float4 d4 = dRow[q];
                    float4 x4 = xRow[q];
                    float v0 = bBase[(4 * q + 0) * NS];
                    float v1 = bBase[(4 * q + 1) * NS];
                    float v2 = bBase[(4 * q + 2) * NS];
                    float v3 = bBase[(4 * q + 3) * NS];
                    h = __expf(d4.x * A) * h + (d4.x * x4.x) * v0;
                    h = __expf(d4.y * A) * h + (d4.y * x4.y) * v1;
                    h = __expf(d4.z * A) * h + (d4.z * x4.z) * v2;
                    h = __expf(d4.w * A) * h + (d4.w * x4.w) * v3;
                    sd += d4.x + d4.y + d4.z + d4.w;
                }
                sA[gid][n] = __expf(A * sd);
                sH[gid][n] = h;
                __syncthreads();

                // prefix over earlier spans (<=7 LDS folds)
                h = 0.f;
                for (int s = 0; s < gid; ++s)
                    h = sA[s][n] * h + sH[s][n];

                // Pass 2: rescan with prefix, reduce over n, gate, store
                int s0 = n & 1, s1 = n & 2;
                for (int q = 0; q < 64; ++q) {
                    float4 d4 = dRow[q];
                    float4 x4 = xRow[q];
                    float bb0 = bBase[(4 * q + 0) * NS];
                    float bb1 = bBase[(4 * q + 1) * NS];
                    float bb2 = bBase[(4 * q + 2) * NS];
                    float bb3 = bBase[(4 * q + 3) * NS];
                    float cc0 = cBase[(4 * q + 0) * NS];
                    float cc1 = cBase[(4 * q + 1) * NS];
                    float cc2 = cBase[(4 * q + 2) * NS];
                    float cc3 = cBase[(4 * q + 3) * NS];
                    h = __expf(d4.x * A) * h + (d4.x * x4.x) * bb0;  float p0 = h * cc0;
                    h = __expf(d4.y * A) * h + (d4.y * x4.y) * bb1;  float p1 = h * cc1;
                    h = __expf(d4.z * A) * h + (d4.z * x4.z) * bb2;  float p2 = h * cc2;
                    h = __expf(d4.w * A) * h + (d4.w * x4.w) * bb3;  float p3 = h * cc3;
                    float u  = s0 ? p1 : p0;
                    float us = s0 ? p0 : p1;
                    u += __shfl_xor(us, 1, 32);
                    float v  = s0 ? p3 : p2;
                    float vs = s0 ? p2 : p3;
                    v += __shfl_xor(vs, 1, 32);
                    float wv  = s1 ? v : u;
                    float wvs = s1 ? u : v;
                    wv += __shfl_xor(wvs, 2, 32);
                    wv += __shfl_xor(wv, 4, 32);
                    wv += __shfl_xor(wv, 8, 32);
                    wv += __shfl_xor(wv, 16, 32);
                    if (n < 4) {
                        int l4 = q * 4;
                        float xs = (n == 0) ? x4.x : (n == 1) ? x4.y
                                 : (n == 2) ? x4.z : x4.w;
                        float yr = wv + Dv * xs;
                        float zv = zRow[l4 + n];
                        yRow[l4 + n] = yr * (zv / (1.f + __expf(-zv)));
                    }
                }
                __syncthreads();   // sA/sH quiescent before next chain
            }
        }
        gbar(layer * 2 + 1);
    }

    // ================= classifier (per group, own batches only) =============
    {
        const float* y3 = ws + (size_t)3 * LSTRIDE + 3 * EDL;
        if (lidx == 0 && tid < NCLASSES) {
            int c = tid;
            for (int bb = b0; bb < bN; ++bb) {
                const float* yp = y3 + (size_t)bb * ED * L_ + (L_ - 1);
                const float* wp = fc_w + c * ED;
                float acc = fc_b[c];
#pragma unroll
                for (int e = 0; e < ED; ++e) acc += yp[(size_t)e * L_] * wp[e];
                out[bb * NCLASSES + c] = acc;
            }
        }
    }
}

// ---------------------------------------------------------------------------
extern "C" void kernel_launch(void* const* d_in, const int* in_sizes, int n_in,
                              void* d_out, int out_size, void* d_ws, size_t ws_size,
                              hipStream_t stream)
{
    const float* x          = (const float*)d_in[0];
    const float* in_proj_w  = (const float*)d_in[1];
    const float* conv_w     = (const float*)d_in[2];
    const float* conv_b     = (const float*)d_in[3];
    const float* x_proj_w   = (const float*)d_in[4];
    const float* dt_proj_w  = (const float*)d_in[5];
    const float* dt_proj_b  = (const float*)d_in[6];
    const float* A_log      = (const float*)d_in[7];
    const float* Dp         = (const float*)d_in[8];
    const float* out_proj_w = (const float*)d_in[9];
    const float* norm_w     = (const float*)d_in[10];
    const float* fc_w       = (const float*)d_in[11];
    const float* fc_b       = (const float*)d_in[12];
    float* ws = (float*)d_ws;

    // zero registration + barrier counters (graph-capturable memset node)
    hipMemsetAsync((void*)(ws + WS_BAR), 0, BAR_BYTES, stream);

    k_all<<<dim3(NBLK), dim3(256), 0, stream>>>(
        x, in_proj_w, conv_w, conv_b, x_proj_w, dt_proj_w, dt_proj_b,
        A_log, Dp, out_proj_w, norm_w, fc_w, fc_b, (float*)d_out, ws);
}